// Round 8
// baseline (198.963 us; speedup 1.0000x reference)
//
#include <hip/hip_runtime.h>
#include <hip/hip_bf16.h>
#include <stdint.h>

// Problem constants (B,T,C fixed by setup_inputs)
#define B_SZ   8
#define T_SEQ  2048
#define C_DIM  1024
#define NH     16
#define HS     64
#define M_DIM  (B_SZ * T_SEQ)   // 16384 rows of the GEMM
#define EXP_SC 10.0f
#define KS_MAX 11.090339630053288f   // log(2^16 - 1)

typedef _Float16 f16;
typedef __attribute__((ext_vector_type(8))) _Float16 f16x8;
typedef __attribute__((ext_vector_type(4))) float f32x4;

// ---------------------------------------------------------------- f16 cast
__global__ void cast_two(const float* __restrict__ xin, f16* __restrict__ xout, int n8x,
                         const float* __restrict__ win, f16* __restrict__ wout, int n8w) {
  int stride = gridDim.x * blockDim.x;
  int t0 = blockIdx.x * blockDim.x + threadIdx.x;
  for (int i = t0; i < n8x; i += stride) {
    const float* p = xin + (size_t)i * 8;
    float4 a = *(const float4*)p;
    float4 b = *(const float4*)(p + 4);
    f16x8 o;
    o[0] = (f16)a.x; o[1] = (f16)a.y; o[2] = (f16)a.z; o[3] = (f16)a.w;
    o[4] = (f16)b.x; o[5] = (f16)b.y; o[6] = (f16)b.z; o[7] = (f16)b.w;
    *(f16x8*)(xout + (size_t)i * 8) = o;
  }
  for (int i = t0; i < n8w; i += stride) {
    const float* p = win + (size_t)i * 8;
    float4 a = *(const float4*)p;
    float4 b = *(const float4*)(p + 4);
    f16x8 o;
    o[0] = (f16)a.x; o[1] = (f16)a.y; o[2] = (f16)a.z; o[3] = (f16)a.w;
    o[4] = (f16)b.x; o[5] = (f16)b.y; o[6] = (f16)b.z; o[7] = (f16)b.w;
    *(f16x8*)(wout + (size_t)i * 8) = o;
  }
}

// --------------------------------------------------- async global->LDS copy
__device__ __forceinline__ void gl_lds16(const f16* g, const f16* l) {
  __builtin_amdgcn_global_load_lds(
      (const __attribute__((address_space(1))) void*)(uintptr_t)(const void*)g,
      (__attribute__((address_space(3))) void*)(uintptr_t)(const void*)l,
      16, 0, 0);
}

// ------------------------------------------------------------- f16 GEMM, 8-phase
// C[m,n] = sum_k A[m,k]*Bt[n,k].  256x256 tile, BK=64, 512 threads (8 waves 2Mx4N),
// per-wave C 128x64 = acc[8][4] f32x4.  4 quadrant-phases per K-tile.
// COUNTED vmcnt (T4, m218): full tile kt+2 issued at kt's P4 (buf[kt+2]=
// buf[kt], readers done at P3 barrier); wait vmcnt(8) = "tile kt+1 landed,
// tile kt+2's 8 loads still flying".  Never drain to 0 in the main loop.
// Tail: clamped dup re-stage of tile 15 keeps the wait branch-free; trailing
// vmcnt(0) drains the dup before endpgm.
// LDS swizzle: source-side XOR (rule #21): lane l stages G[row][slot^(row&7)]
// into linear LDS[row][slot]; reader reads LDS[row][slot^(row&7)] -> G[row][slot].
// (R6 measured: SQ_LDS_BANK_CONFLICT == 0.)
__global__ __launch_bounds__(512, 2)
void gemm_bt_f16_8p(const f16* __restrict__ A,
                    const f16* __restrict__ Bt,
                    float* __restrict__ C) {
  __shared__ f16 As[2][2][128 * 64];   // [dbuf][M-half][128 rows x 64 cols]
  __shared__ f16 Bs[2][2][128 * 64];   // [dbuf][N-half][...]           128KB total

  const int tid = threadIdx.x;
  const int w = tid >> 6, l = tid & 63;
  const int wm = w >> 2, wn = w & 3;          // 2M x 4N waves

  // XCD-bijective swizzle: nwg=256, 8 XCDs -> 32 contiguous wgids each
  const int q = blockIdx.x;
  const int wgid = (q & 7) * 32 + (q >> 3);
  const int bm = wgid >> 2;                   // 0..63
  const int bn = wgid & 3;                    // 0..3

  // ---- staging per-lane constants (pre-swizzled global source)
  const int srow = l >> 3;                    // row within 8-row group == row&7
  const int sswz = (((l & 7) ^ srow)) << 3;   // swizzled col (elems)
  const size_t a_lane = (size_t)(bm * 256 + w * 8 + srow) * C_DIM + sswz;
  const size_t b_lane = (size_t)(bn * 256 + w * 8 + srow) * C_DIM + sswz;
  const int lds_w = w * 512;                  // wave slice inside one call block

  // ---- fragment per-lane constants (swizzled LDS read)
  const int fr = l & 15;
  const int fk = l >> 4;                      // k-slot within 32
  const int ck0 = ((fk) ^ (l & 7)) << 3;      // kk=0 col (elems)
  const int ck1 = ((4 + fk) ^ (l & 7)) << 3;  // kk=1 col

  const f32x4 zero = {0.f, 0.f, 0.f, 0.f};
  f32x4 acc[8][4];
#pragma unroll
  for (int i = 0; i < 8; ++i)
#pragma unroll
    for (int j = 0; j < 4; ++j) acc[i][j] = zero;

  f16x8 af[4][2], b0[2][2], b1[2][2];

#define STAGE_FULL(ktile, buf) do {                                           \
    size_t ko = (size_t)(ktile) * 64;                                         \
    gl_lds16(A + a_lane + ko,                         &As[buf][0][lds_w]);        \
    gl_lds16(A + a_lane + ko + (size_t) 64 * C_DIM,   &As[buf][0][lds_w + 4096]); \
    gl_lds16(A + a_lane + ko + (size_t)128 * C_DIM,   &As[buf][1][lds_w]);        \
    gl_lds16(A + a_lane + ko + (size_t)192 * C_DIM,   &As[buf][1][lds_w + 4096]); \
    gl_lds16(Bt + b_lane + ko,                        &Bs[buf][0][lds_w]);        \
    gl_lds16(Bt + b_lane + ko + (size_t) 64 * C_DIM,  &Bs[buf][0][lds_w + 4096]); \
    gl_lds16(Bt + b_lane + ko + (size_t)128 * C_DIM,  &Bs[buf][1][lds_w]);        \
    gl_lds16(Bt + b_lane + ko + (size_t)192 * C_DIM,  &Bs[buf][1][lds_w + 4096]); \
  } while (0)

#define MFMA16(mi, ni, BREG) do {                                            \
    _Pragma("unroll") for (int kk = 0; kk < 2; ++kk)                         \
    _Pragma("unroll") for (int i = 0; i < 4; ++i)                            \
    _Pragma("unroll") for (int j = 0; j < 2; ++j)                            \
      acc[(mi)*4 + i][(ni)*2 + j] = __builtin_amdgcn_mfma_f32_16x16x32_f16(  \
          af[i][kk], BREG[j][kk], acc[(mi)*4 + i][(ni)*2 + j], 0, 0, 0);     \
  } while (0)

  // prologue: stage tiles 0 and 1 (16 loads); wait for tile 0 only.
  STAGE_FULL(0, 0);
  STAGE_FULL(1, 1);
  asm volatile("s_waitcnt vmcnt(8)" ::: "memory");
  __syncthreads();

  for (int kt = 0; kt < 16; ++kt) {
    const int cur = kt & 1;
    const f16* Ab = &As[cur][wm][0];
    const f16* Bb = &Bs[cur][wn >> 1][(wn & 1) * 4096];

    // ---- phase 1: Q(mi=0, ni=0)  [12 ds_reads]
#pragma unroll
    for (int i = 0; i < 4; ++i) {
      af[i][0] = *(const f16x8*)(Ab + (i * 16 + fr) * 64 + ck0);
      af[i][1] = *(const f16x8*)(Ab + (i * 16 + fr) * 64 + ck1);
    }
#pragma unroll
    for (int j = 0; j < 2; ++j) {
      b0[j][0] = *(const f16x8*)(Bb + (j * 16 + fr) * 64 + ck0);
      b0[j][1] = *(const f16x8*)(Bb + (j * 16 + fr) * 64 + ck1);
    }
    __builtin_amdgcn_s_barrier();
    asm volatile("s_waitcnt lgkmcnt(0)" ::: "memory");
    __builtin_amdgcn_s_setprio(1);
    MFMA16(0, 0, b0);
    __builtin_amdgcn_s_setprio(0);
    __builtin_amdgcn_s_barrier();

    // ---- phase 2: Q(0,1)  [4 ds_reads]
#pragma unroll
    for (int j = 0; j < 2; ++j) {
      b1[j][0] = *(const f16x8*)(Bb + ((2 + j) * 16 + fr) * 64 + ck0);
      b1[j][1] = *(const f16x8*)(Bb + ((2 + j) * 16 + fr) * 64 + ck1);
    }
    __builtin_amdgcn_s_barrier();
    asm volatile("s_waitcnt lgkmcnt(0)" ::: "memory");
    __builtin_amdgcn_s_setprio(1);
    MFMA16(0, 1, b1);
    __builtin_amdgcn_s_setprio(0);
    __builtin_amdgcn_s_barrier();

    // ---- phase 3: Q(1,1)  [8 ds_reads: A rows 64..127]
#pragma unroll
    for (int i = 0; i < 4; ++i) {
      af[i][0] = *(const f16x8*)(Ab + (64 + i * 16 + fr) * 64 + ck0);
      af[i][1] = *(const f16x8*)(Ab + (64 + i * 16 + fr) * 64 + ck1);
    }
    __builtin_amdgcn_s_barrier();
    asm volatile("s_waitcnt lgkmcnt(0)" ::: "memory");
    __builtin_amdgcn_s_setprio(1);
    MFMA16(1, 1, b1);
    __builtin_amdgcn_s_setprio(0);
    __builtin_amdgcn_s_barrier();

    // ---- phase 4: Q(1,0) + issue tile kt+2 (buf[kt+2]=cur; readers done @P3)
    if (kt < 15) {                       // wave-uniform branch, no barriers inside
      int kt2 = kt + 2; if (kt2 > 15) kt2 = 15;   // kt=14: dup tile15 (harmless)
      STAGE_FULL(kt2, cur);
    }
    __builtin_amdgcn_s_setprio(1);
    MFMA16(1, 0, b0);
    __builtin_amdgcn_s_setprio(0);
    // counted wait (T4): tile kt+1 landed; tile kt+2's 8 loads stay in flight
    asm volatile("s_waitcnt vmcnt(8)" ::: "memory");
    __builtin_amdgcn_s_barrier();
  }
  // drain any still-flying dup-stage before LDS goes away at endpgm
  asm volatile("s_waitcnt vmcnt(0)" ::: "memory");
#undef STAGE_FULL
#undef MFMA16

  // epilogue: C/D layout col = lane&15, row = (lane>>4)*4 + reg  [m89-verified]
  const int orow0 = bm * 256 + wm * 128 + (l >> 4) * 4;
  const int ocol0 = bn * 256 + wn * 64 + (l & 15);
#pragma unroll
  for (int i = 0; i < 8; ++i)
#pragma unroll
    for (int j = 0; j < 4; ++j)
#pragma unroll
      for (int r = 0; r < 4; ++r)
        C[(size_t)(orow0 + i * 16 + r) * C_DIM + ocol0 + j * 16] = acc[i][j][r];
}

// -------------------------------------------- fused leaky-scan + L2-norm + scale
__global__ __launch_bounds__(256)
void scan_norm(const float* __restrict__ kbuf,      // (B*T, C) f32
               const float* __restrict__ beta_p,    // 16
               const float* __restrict__ ks_p,      // 16
               const int* __restrict__ sp_p,        // 1
               float* __restrict__ out) {           // (B, NH, T, HS)
  const int l = threadIdx.x & 63;
  const int gw = blockIdx.x * 4 + (threadIdx.x >> 6);  // 4096 waves total
  const int c = gw & 31;          // T/64 = 32 chunks
  const int h = (gw >> 5) & 15;
  const int b = gw >> 9;

  const float beta = fabsf(beta_p[h]) * EXP_SC;
  const float a = expf(-beta);
  const float sp = (float)sp_p[0];
  const float scale = expf(fminf(sp * EXP_SC * ks_p[h], KS_MAX));

  const float* kp = kbuf + (size_t)b * T_SEQ * C_DIM + h * HS + l;
  float* op = out + ((size_t)(b * NH + h) * T_SEQ) * HS + l;

  const int t0 = c * 64;
  float y = 0.f;
  int s = (t0 >= 64) ? (t0 - 64) : 0;   // 64-step lookback: trunc ~1.3e-14
#pragma unroll 8
  for (; s < t0; ++s)
    y = fmaf(a, y, kp[(size_t)s * C_DIM]);

#pragma unroll 4
  for (int t = t0; t < t0 + 64; ++t) {
    y = fmaf(a, y, kp[(size_t)t * C_DIM]);
    float sq = y * y;
#pragma unroll
    for (int m = 1; m < 64; m <<= 1)
      sq += __shfl_xor(sq, m, 64);
    float nrm = sqrtf(sq) + 1e-10f;
    op[(size_t)t * HS] = y * (scale / nrm);
  }
}

// --------------------------------------------------------------- launcher
extern "C" void kernel_launch(void* const* d_in, const int* in_sizes, int n_in,
                              void* d_out, int out_size, void* d_ws, size_t ws_size,
                              hipStream_t stream) {
  const float* x      = (const float*)d_in[0];   // (8,2048,1024) f32
  const float* Wk     = (const float*)d_in[1];   // (1024,1024) f32
  const float* beta   = (const float*)d_in[2];   // (16) f32
  const float* kscale = (const float*)d_in[3];   // (16) f32
  const int*   spow   = (const int*)d_in[4];     // (1) int
  float* out = (float*)d_out;

  // workspace layout: x_f16 (32MB) | W_f16 (2MB) | k_f32 (64MB)  ~= 98MB
  f16* x_h = (f16*)d_ws;
  f16* W_h = x_h + (size_t)M_DIM * C_DIM;
  float* kbuf = (float*)(W_h + (size_t)C_DIM * C_DIM);

  cast_two<<<2048, 256, 0, stream>>>(x, x_h, (M_DIM * C_DIM) / 8,
                                     Wk, W_h, (C_DIM * C_DIM) / 8);
  gemm_bt_f16_8p<<<dim3((M_DIM / 256) * (C_DIM / 256)), 512, 0, stream>>>(x_h, W_h, kbuf);
  scan_norm<<<1024, 256, 0, stream>>>(kbuf, beta, kscale, spow, out);
}

// Round 11
// 198.601 us; speedup vs baseline: 1.0018x; 1.0018x over previous
//
#include <hip/hip_runtime.h>
#include <hip/hip_bf16.h>
#include <stdint.h>

// Problem constants (B,T,C fixed by setup_inputs)
#define B_SZ   8
#define T_SEQ  2048
#define C_DIM  1024
#define NH     16
#define HS     64
#define M_DIM  (B_SZ * T_SEQ)   // 16384 rows of the GEMM
#define EXP_SC 10.0f
#define KS_MAX 11.090339630053288f   // log(2^16 - 1)

typedef _Float16 f16;
typedef __attribute__((ext_vector_type(8))) _Float16 f16x8;
typedef __attribute__((ext_vector_type(2))) _Float16 f16x2;
typedef __attribute__((ext_vector_type(4))) float f32x4;

// ---------------------------------------------------------------- f16 cast
__global__ void cast_two(const float* __restrict__ xin, f16* __restrict__ xout, int n8x,
                         const float* __restrict__ win, f16* __restrict__ wout, int n8w) {
  int stride = gridDim.x * blockDim.x;
  int t0 = blockIdx.x * blockDim.x + threadIdx.x;
  for (int i = t0; i < n8x; i += stride) {
    const float* p = xin + (size_t)i * 8;
    float4 a = *(const float4*)p;
    float4 b = *(const float4*)(p + 4);
    f16x8 o;
    o[0] = (f16)a.x; o[1] = (f16)a.y; o[2] = (f16)a.z; o[3] = (f16)a.w;
    o[4] = (f16)b.x; o[5] = (f16)b.y; o[6] = (f16)b.z; o[7] = (f16)b.w;
    *(f16x8*)(xout + (size_t)i * 8) = o;
  }
  for (int i = t0; i < n8w; i += stride) {
    const float* p = win + (size_t)i * 8;
    float4 a = *(const float4*)p;
    float4 b = *(const float4*)(p + 4);
    f16x8 o;
    o[0] = (f16)a.x; o[1] = (f16)a.y; o[2] = (f16)a.z; o[3] = (f16)a.w;
    o[4] = (f16)b.x; o[5] = (f16)b.y; o[6] = (f16)b.z; o[7] = (f16)b.w;
    *(f16x8*)(wout + (size_t)i * 8) = o;
  }
}

// --------------------------------------------------- async global->LDS copy
__device__ __forceinline__ void gl_lds16(const f16* g, const f16* l) {
  __builtin_amdgcn_global_load_lds(
      (const __attribute__((address_space(1))) void*)(uintptr_t)(const void*)g,
      (__attribute__((address_space(3))) void*)(uintptr_t)(const void*)l,
      16, 0, 0);
}

// ------------------------------------------------------------- f16 GEMM, 8-phase
// R6 schedule (measured best: 43.4us, MfmaUtil 29%, conflicts 0).  256x256 tile,
// BK=64, 512 threads (8 waves 2Mx4N), 4 quadrant-phases per K-tile:
// P1{12 ds + STAGE_A(next)} P2{4 ds + STAGE_B(next)} P3{8 ds} P4{MFMA only,
// vmcnt(0) on ~2-phase-old loads}.  R9 change: C-write is f16 into
// scan-friendly [B][NH][T][HS] layout (WRITE 66->33 MB, epilogue burst halved).
// LDS swizzle: source-side XOR (rule #21); R6 measured SQ_LDS_BANK_CONFLICT==0.
__global__ __launch_bounds__(512, 2)
void gemm_bt_f16_8p(const f16* __restrict__ A,
                    const f16* __restrict__ Bt,
                    f16* __restrict__ KB) {
  __shared__ f16 As[2][2][128 * 64];   // [dbuf][M-half][128 rows x 64 cols]
  __shared__ f16 Bs[2][2][128 * 64];   // [dbuf][N-half][...]           128KB total

  const int tid = threadIdx.x;
  const int w = tid >> 6, l = tid & 63;
  const int wm = w >> 2, wn = w & 3;          // 2M x 4N waves

  // XCD-bijective swizzle: nwg=256, 8 XCDs -> 32 contiguous wgids each
  const int q = blockIdx.x;
  const int wgid = (q & 7) * 32 + (q >> 3);
  const int bm = wgid >> 2;                   // 0..63
  const int bn = wgid & 3;                    // 0..3

  // ---- staging per-lane constants (pre-swizzled global source)
  const int srow = l >> 3;                    // row within 8-row group == row&7
  const int sswz = (((l & 7) ^ srow)) << 3;   // swizzled col (elems)
  const size_t a_lane = (size_t)(bm * 256 + w * 8 + srow) * C_DIM + sswz;
  const size_t b_lane = (size_t)(bn * 256 + w * 8 + srow) * C_DIM + sswz;
  const int lds_w = w * 512;                  // wave slice inside one call block

  // ---- fragment per-lane constants (swizzled LDS read)
  const int fr = l & 15;
  const int fk = l >> 4;                      // k-slot within 32
  const int ck0 = ((fk) ^ (l & 7)) << 3;      // kk=0 col (elems)
  const int ck1 = ((4 + fk) ^ (l & 7)) << 3;  // kk=1 col

  const f32x4 zero = {0.f, 0.f, 0.f, 0.f};
  f32x4 acc[8][4];
#pragma unroll
  for (int i = 0; i < 8; ++i)
#pragma unroll
    for (int j = 0; j < 4; ++j) acc[i][j] = zero;

  f16x8 af[4][2], b0[2][2], b1[2][2];

#define STAGE_A(buf, kt) do {                                                \
    size_t ko = (size_t)(kt) * 64;                                           \
    gl_lds16(A + a_lane + ko,                         &As[buf][0][lds_w]);        \
    gl_lds16(A + a_lane + ko + (size_t) 64 * C_DIM,   &As[buf][0][lds_w + 4096]); \
    gl_lds16(A + a_lane + ko + (size_t)128 * C_DIM,   &As[buf][1][lds_w]);        \
    gl_lds16(A + a_lane + ko + (size_t)192 * C_DIM,   &As[buf][1][lds_w + 4096]); \
  } while (0)
#define STAGE_B(buf, kt) do {                                                \
    size_t ko = (size_t)(kt) * 64;                                           \
    gl_lds16(Bt + b_lane + ko,                        &Bs[buf][0][lds_w]);        \
    gl_lds16(Bt + b_lane + ko + (size_t) 64 * C_DIM,  &Bs[buf][0][lds_w + 4096]); \
    gl_lds16(Bt + b_lane + ko + (size_t)128 * C_DIM,  &Bs[buf][1][lds_w]);        \
    gl_lds16(Bt + b_lane + ko + (size_t)192 * C_DIM,  &Bs[buf][1][lds_w + 4096]); \
  } while (0)

#define MFMA16(mi, ni, BREG) do {                                            \
    _Pragma("unroll") for (int kk = 0; kk < 2; ++kk)                         \
    _Pragma("unroll") for (int i = 0; i < 4; ++i)                            \
    _Pragma("unroll") for (int j = 0; j < 2; ++j)                            \
      acc[(mi)*4 + i][(ni)*2 + j] = __builtin_amdgcn_mfma_f32_16x16x32_f16(  \
          af[i][kk], BREG[j][kk], acc[(mi)*4 + i][(ni)*2 + j], 0, 0, 0);     \
  } while (0)

  // prologue: stage K-tile 0 into buf 0
  STAGE_A(0, 0); STAGE_B(0, 0);
  __syncthreads();                     // drains vmcnt -> buf0 ready

  for (int kt = 0; kt < 16; ++kt) {
    const int cur = kt & 1;
    const f16* Ab = &As[cur][wm][0];
    const f16* Bb = &Bs[cur][wn >> 1][(wn & 1) * 4096];

    // ---- phase 1: Q(0,0)  [12 ds_reads + A-stage issue]
#pragma unroll
    for (int i = 0; i < 4; ++i) {
      af[i][0] = *(const f16x8*)(Ab + (i * 16 + fr) * 64 + ck0);
      af[i][1] = *(const f16x8*)(Ab + (i * 16 + fr) * 64 + ck1);
    }
#pragma unroll
    for (int j = 0; j < 2; ++j) {
      b0[j][0] = *(const f16x8*)(Bb + (j * 16 + fr) * 64 + ck0);
      b0[j][1] = *(const f16x8*)(Bb + (j * 16 + fr) * 64 + ck1);
    }
    if (kt < 15) STAGE_A(cur ^ 1, kt + 1);
    __builtin_amdgcn_s_barrier();
    asm volatile("s_waitcnt lgkmcnt(0)" ::: "memory");
    __builtin_amdgcn_s_setprio(1);
    MFMA16(0, 0, b0);
    __builtin_amdgcn_s_setprio(0);
    __builtin_amdgcn_s_barrier();

    // ---- phase 2: Q(0,1)  [4 ds_reads + B-stage issue]
#pragma unroll
    for (int j = 0; j < 2; ++j) {
      b1[j][0] = *(const f16x8*)(Bb + ((2 + j) * 16 + fr) * 64 + ck0);
      b1[j][1] = *(const f16x8*)(Bb + ((2 + j) * 16 + fr) * 64 + ck1);
    }
    if (kt < 15) STAGE_B(cur ^ 1, kt + 1);
    __builtin_amdgcn_s_barrier();
    asm volatile("s_waitcnt lgkmcnt(0)" ::: "memory");
    __builtin_amdgcn_s_setprio(1);
    MFMA16(0, 1, b1);
    __builtin_amdgcn_s_setprio(0);
    __builtin_amdgcn_s_barrier();

    // ---- phase 3: Q(1,1)  [8 ds_reads: A rows 64..127]
#pragma unroll
    for (int i = 0; i < 4; ++i) {
      af[i][0] = *(const f16x8*)(Ab + (64 + i * 16 + fr) * 64 + ck0);
      af[i][1] = *(const f16x8*)(Ab + (64 + i * 16 + fr) * 64 + ck1);
    }
    __builtin_amdgcn_s_barrier();
    asm volatile("s_waitcnt lgkmcnt(0)" ::: "memory");
    __builtin_amdgcn_s_setprio(1);
    MFMA16(1, 1, b1);
    __builtin_amdgcn_s_setprio(0);
    __builtin_amdgcn_s_barrier();

    // ---- phase 4: Q(1,0)  [no ds_reads; b0 still live]
    __builtin_amdgcn_s_setprio(1);
    MFMA16(1, 0, b0);
    __builtin_amdgcn_s_setprio(0);
    asm volatile("s_waitcnt vmcnt(0)" ::: "memory");  // ~2-phase-old loads
    __builtin_amdgcn_s_barrier();
  }
#undef STAGE_A
#undef STAGE_B
#undef MFMA16

  // epilogue: f16 write into scan-friendly [B][NH][T][HS] layout.
  // C/D layout: col = lane&15, row = (lane>>4)*4 + reg  [m89-verified].
  // n = bn*256 + wn*64 + j*16 + (l&15) -> h = bn*4+wn (wave-uniform),
  // d = j*16 + (l&15).  m = bm*256 + ... -> b = bm>>3 (256-row tiles are
  // batch-aligned), t = (bm&7)*256 + wm*128 + (l>>4)*4 + i*16 + r.
  const int b   = bm >> 3;                               // batch
  const int tb  = (bm & 7) * 256 + wm * 128 + (l >> 4) * 4; // t of reg r=0,i=0
  const int h   = bn * 4 + wn;                           // wave-uniform head
  f16* kb = KB + ((size_t)(b * NH + h) * T_SEQ + tb) * HS + (l & 15);
#pragma unroll
  for (int i = 0; i < 8; ++i)
#pragma unroll
    for (int j = 0; j < 4; ++j)
#pragma unroll
      for (int r = 0; r < 4; ++r)
        kb[(size_t)(i * 16 + r) * HS + j * 16] = (f16)acc[i][j][r];
}

// -------------------------------------------- fused leaky-scan + L2-norm + scale
// y[t] = e^{-beta_h} * y[t-1] + k[t] ; out = y/(||y||_2 + 1e-10) * scale_h
// kbuf is f16 [B][NH][T][HS] -> each (b,h) stream is a contiguous 256KB block.
// 32 lanes per row (f16x2/lane), 2 streams per wave.  64-step lookback split
// into two independent 32-chains (combined via a^32): trunc ~1.3e-14.
__global__ __launch_bounds__(256)
void scan_norm2(const f16* __restrict__ kb,        // (B,NH,T,HS) f16
                const float* __restrict__ beta_p,  // 16
                const float* __restrict__ ks_p,    // 16
                const int* __restrict__ sp_p,      // 1
                float* __restrict__ out) {         // (B, NH, T, HS) f32
  const int l = threadIdx.x & 63;
  const int g = l & 31;                               // lane in 32-group
  const int gw = blockIdx.x * 4 + (threadIdx.x >> 6); // 2048 waves
  const int sid = gw * 2 + (l >> 5);                  // 0..4095 streams
  const int c = sid & 31;          // T/64 = 32 chunks
  const int h = (sid >> 5) & 15;
  const int b = sid >> 9;

  const float beta = fabsf(beta_p[h]) * EXP_SC;
  const float a = expf(-beta);
  float a2 = a * a, a4 = a2 * a2, a8 = a4 * a4, a16 = a8 * a8;
  const float a32 = a16 * a16;
  const float sp = (float)sp_p[0];
  const float scale = expf(fminf(sp * EXP_SC * ks_p[h], KS_MAX));

  const f16* kp = kb + (size_t)(b * NH + h) * T_SEQ * HS + 2 * g;
  float* op = out + (size_t)(b * NH + h) * T_SEQ * HS + 2 * g;

  const int t0 = c * 64;
  float y0 = 0.f, y1 = 0.f;
  if (t0) {
    // two independent 32-step chains over [t0-64, t0)
    float p0 = 0.f, p1 = 0.f, q0 = 0.f, q1 = 0.f;
#pragma unroll 4
    for (int s = t0 - 64; s < t0 - 32; ++s) {
      f16x2 v = *(const f16x2*)(kp + (size_t)s * HS);
      p0 = fmaf(a, p0, (float)v[0]);
      p1 = fmaf(a, p1, (float)v[1]);
    }
#pragma unroll 4
    for (int s = t0 - 32; s < t0; ++s) {
      f16x2 v = *(const f16x2*)(kp + (size_t)s * HS);
      q0 = fmaf(a, q0, (float)v[0]);
      q1 = fmaf(a, q1, (float)v[1]);
    }
    y0 = fmaf(p0, a32, q0);
    y1 = fmaf(p1, a32, q1);
  }

#pragma unroll 4
  for (int t = t0; t < t0 + 64; ++t) {
    f16x2 v = *(const f16x2*)(kp + (size_t)t * HS);
    y0 = fmaf(a, y0, (float)v[0]);
    y1 = fmaf(a, y1, (float)v[1]);
    float sq = fmaf(y0, y0, y1 * y1);
#pragma unroll
    for (int m = 1; m < 32; m <<= 1)
      sq += __shfl_xor(sq, m, 64);     // masks <=16: stays within 32-group
    float inv = scale / (sqrtf(sq) + 1e-10f);
    float2 o; o.x = y0 * inv; o.y = y1 * inv;
    *(float2*)(op + (size_t)t * HS) = o;
  }
}

// --------------------------------------------------------------- launcher
extern "C" void kernel_launch(void* const* d_in, const int* in_sizes, int n_in,
                              void* d_out, int out_size, void* d_ws, size_t ws_size,
                              hipStream_t stream) {
  const float* x      = (const float*)d_in[0];   // (8,2048,1024) f32
  const float* Wk     = (const float*)d_in[1];   // (1024,1024) f32
  const float* beta   = (const float*)d_in[2];   // (16) f32
  const float* kscale = (const float*)d_in[3];   // (16) f32
  const int*   spow   = (const int*)d_in[4];     // (1) int
  float* out = (float*)d_out;

  // workspace layout: x_f16 (32MB) | W_f16 (2MB) | kb f16 (32MB)  ~= 66MB
  f16* x_h = (f16*)d_ws;
  f16* W_h = x_h + (size_t)M_DIM * C_DIM;
  f16* kb  = W_h + (size_t)C_DIM * C_DIM;

  cast_two<<<2048, 256, 0, stream>>>(x, x_h, (M_DIM * C_DIM) / 8,
                                     Wk, W_h, (C_DIM * C_DIM) / 8);
  gemm_bt_f16_8p<<<dim3((M_DIM / 256) * (C_DIM / 256)), 512, 0, stream>>>(x_h, W_h, kb);
  scan_norm2<<<512, 256, 0, stream>>>(kb, beta, kscale, spow, out);
}

// Round 13
// 172.118 us; speedup vs baseline: 1.1560x; 1.1539x over previous
//
#include <hip/hip_runtime.h>
#include <hip/hip_bf16.h>
#include <stdint.h>

// Problem constants (B,T,C fixed by setup_inputs)
#define B_SZ   8
#define T_SEQ  2048
#define C_DIM  1024
#define NH     16
#define HS     64
#define M_DIM  (B_SZ * T_SEQ)   // 16384 rows of the GEMM
#define EXP_SC 10.0f
#define KS_MAX 11.090339630053288f   // log(2^16 - 1)

typedef _Float16 f16;
typedef __attribute__((ext_vector_type(8))) _Float16 f16x8;
typedef __attribute__((ext_vector_type(4))) float f32x4;

// ---------------------------------------------------------------- f16 cast
__global__ void cast_two(const float* __restrict__ xin, f16* __restrict__ xout, int n8x,
                         const float* __restrict__ win, f16* __restrict__ wout, int n8w) {
  int stride = gridDim.x * blockDim.x;
  int t0 = blockIdx.x * blockDim.x + threadIdx.x;
  for (int i = t0; i < n8x; i += stride) {
    const float* p = xin + (size_t)i * 8;
    float4 a = *(const float4*)p;
    float4 b = *(const float4*)(p + 4);
    f16x8 o;
    o[0] = (f16)a.x; o[1] = (f16)a.y; o[2] = (f16)a.z; o[3] = (f16)a.w;
    o[4] = (f16)b.x; o[5] = (f16)b.y; o[6] = (f16)b.z; o[7] = (f16)b.w;
    *(f16x8*)(xout + (size_t)i * 8) = o;
  }
  for (int i = t0; i < n8w; i += stride) {
    const float* p = win + (size_t)i * 8;
    float4 a = *(const float4*)p;
    float4 b = *(const float4*)(p + 4);
    f16x8 o;
    o[0] = (f16)a.x; o[1] = (f16)a.y; o[2] = (f16)a.z; o[3] = (f16)a.w;
    o[4] = (f16)b.x; o[5] = (f16)b.y; o[6] = (f16)b.z; o[7] = (f16)b.w;
    *(f16x8*)(wout + (size_t)i * 8) = o;
  }
}

// --------------------------------------------------- async global->LDS copy
__device__ __forceinline__ void gl_lds16(const f16* g, const f16* l) {
  __builtin_amdgcn_global_load_lds(
      (const __attribute__((address_space(1))) void*)(uintptr_t)(const void*)g,
      (__attribute__((address_space(3))) void*)(uintptr_t)(const void*)l,
      16, 0, 0);
}

// ------------------------------------------------------------- f16 GEMM, 8-phase
// R6 schedule (measured best; R11: below scan in top-5, ~<=40us).  256x256 tile,
// BK=64, 512 threads (8 waves 2Mx4N), 4 quadrant-phases per K-tile.
// C-write: f16 into scan-friendly [B][NH][T][HS] layout.
// LDS swizzle: source-side XOR (rule #21); measured SQ_LDS_BANK_CONFLICT==0.
__global__ __launch_bounds__(512, 2)
void gemm_bt_f16_8p(const f16* __restrict__ A,
                    const f16* __restrict__ Bt,
                    f16* __restrict__ KB) {
  __shared__ f16 As[2][2][128 * 64];   // [dbuf][M-half][128 rows x 64 cols]
  __shared__ f16 Bs[2][2][128 * 64];   // [dbuf][N-half][...]           128KB total

  const int tid = threadIdx.x;
  const int w = tid >> 6, l = tid & 63;
  const int wm = w >> 2, wn = w & 3;          // 2M x 4N waves

  // XCD-bijective swizzle: nwg=256, 8 XCDs -> 32 contiguous wgids each
  const int q = blockIdx.x;
  const int wgid = (q & 7) * 32 + (q >> 3);
  const int bm = wgid >> 2;                   // 0..63
  const int bn = wgid & 3;                    // 0..3

  // ---- staging per-lane constants (pre-swizzled global source)
  const int srow = l >> 3;                    // row within 8-row group == row&7
  const int sswz = (((l & 7) ^ srow)) << 3;   // swizzled col (elems)
  const size_t a_lane = (size_t)(bm * 256 + w * 8 + srow) * C_DIM + sswz;
  const size_t b_lane = (size_t)(bn * 256 + w * 8 + srow) * C_DIM + sswz;
  const int lds_w = w * 512;                  // wave slice inside one call block

  // ---- fragment per-lane constants (swizzled LDS read)
  const int fr = l & 15;
  const int fk = l >> 4;                      // k-slot within 32
  const int ck0 = ((fk) ^ (l & 7)) << 3;      // kk=0 col (elems)
  const int ck1 = ((4 + fk) ^ (l & 7)) << 3;  // kk=1 col

  const f32x4 zero = {0.f, 0.f, 0.f, 0.f};
  f32x4 acc[8][4];
#pragma unroll
  for (int i = 0; i < 8; ++i)
#pragma unroll
    for (int j = 0; j < 4; ++j) acc[i][j] = zero;

  f16x8 af[4][2], b0[2][2], b1[2][2];

#define STAGE_A(buf, kt) do {                                                \
    size_t ko = (size_t)(kt) * 64;                                           \
    gl_lds16(A + a_lane + ko,                         &As[buf][0][lds_w]);        \
    gl_lds16(A + a_lane + ko + (size_t) 64 * C_DIM,   &As[buf][0][lds_w + 4096]); \
    gl_lds16(A + a_lane + ko + (size_t)128 * C_DIM,   &As[buf][1][lds_w]);        \
    gl_lds16(A + a_lane + ko + (size_t)192 * C_DIM,   &As[buf][1][lds_w + 4096]); \
  } while (0)
#define STAGE_B(buf, kt) do {                                                \
    size_t ko = (size_t)(kt) * 64;                                           \
    gl_lds16(Bt + b_lane + ko,                        &Bs[buf][0][lds_w]);        \
    gl_lds16(Bt + b_lane + ko + (size_t) 64 * C_DIM,  &Bs[buf][0][lds_w + 4096]); \
    gl_lds16(Bt + b_lane + ko + (size_t)128 * C_DIM,  &Bs[buf][1][lds_w]);        \
    gl_lds16(Bt + b_lane + ko + (size_t)192 * C_DIM,  &Bs[buf][1][lds_w + 4096]); \
  } while (0)

#define MFMA16(mi, ni, BREG) do {                                            \
    _Pragma("unroll") for (int kk = 0; kk < 2; ++kk)                         \
    _Pragma("unroll") for (int i = 0; i < 4; ++i)                            \
    _Pragma("unroll") for (int j = 0; j < 2; ++j)                            \
      acc[(mi)*4 + i][(ni)*2 + j] = __builtin_amdgcn_mfma_f32_16x16x32_f16(  \
          af[i][kk], BREG[j][kk], acc[(mi)*4 + i][(ni)*2 + j], 0, 0, 0);     \
  } while (0)

  // prologue: stage K-tile 0 into buf 0
  STAGE_A(0, 0); STAGE_B(0, 0);
  __syncthreads();                     // drains vmcnt -> buf0 ready

  for (int kt = 0; kt < 16; ++kt) {
    const int cur = kt & 1;
    const f16* Ab = &As[cur][wm][0];
    const f16* Bb = &Bs[cur][wn >> 1][(wn & 1) * 4096];

    // ---- phase 1: Q(0,0)  [12 ds_reads + A-stage issue]
#pragma unroll
    for (int i = 0; i < 4; ++i) {
      af[i][0] = *(const f16x8*)(Ab + (i * 16 + fr) * 64 + ck0);
      af[i][1] = *(const f16x8*)(Ab + (i * 16 + fr) * 64 + ck1);
    }
#pragma unroll
    for (int j = 0; j < 2; ++j) {
      b0[j][0] = *(const f16x8*)(Bb + (j * 16 + fr) * 64 + ck0);
      b0[j][1] = *(const f16x8*)(Bb + (j * 16 + fr) * 64 + ck1);
    }
    if (kt < 15) STAGE_A(cur ^ 1, kt + 1);
    __builtin_amdgcn_s_barrier();
    asm volatile("s_waitcnt lgkmcnt(0)" ::: "memory");
    __builtin_amdgcn_s_setprio(1);
    MFMA16(0, 0, b0);
    __builtin_amdgcn_s_setprio(0);
    __builtin_amdgcn_s_barrier();

    // ---- phase 2: Q(0,1)  [4 ds_reads + B-stage issue]
#pragma unroll
    for (int j = 0; j < 2; ++j) {
      b1[j][0] = *(const f16x8*)(Bb + ((2 + j) * 16 + fr) * 64 + ck0);
      b1[j][1] = *(const f16x8*)(Bb + ((2 + j) * 16 + fr) * 64 + ck1);
    }
    if (kt < 15) STAGE_B(cur ^ 1, kt + 1);
    __builtin_amdgcn_s_barrier();
    asm volatile("s_waitcnt lgkmcnt(0)" ::: "memory");
    __builtin_amdgcn_s_setprio(1);
    MFMA16(0, 1, b1);
    __builtin_amdgcn_s_setprio(0);
    __builtin_amdgcn_s_barrier();

    // ---- phase 3: Q(1,1)  [8 ds_reads: A rows 64..127]
#pragma unroll
    for (int i = 0; i < 4; ++i) {
      af[i][0] = *(const f16x8*)(Ab + (64 + i * 16 + fr) * 64 + ck0);
      af[i][1] = *(const f16x8*)(Ab + (64 + i * 16 + fr) * 64 + ck1);
    }
    __builtin_amdgcn_s_barrier();
    asm volatile("s_waitcnt lgkmcnt(0)" ::: "memory");
    __builtin_amdgcn_s_setprio(1);
    MFMA16(1, 1, b1);
    __builtin_amdgcn_s_setprio(0);
    __builtin_amdgcn_s_barrier();

    // ---- phase 4: Q(1,0)  [no ds_reads; b0 still live]
    __builtin_amdgcn_s_setprio(1);
    MFMA16(1, 0, b0);
    __builtin_amdgcn_s_setprio(0);
    asm volatile("s_waitcnt vmcnt(0)" ::: "memory");  // ~2-phase-old loads
    __builtin_amdgcn_s_barrier();
  }
#undef STAGE_A
#undef STAGE_B
#undef MFMA16

  // epilogue: f16 write into scan-friendly [B][NH][T][HS] layout.
  // C/D layout: col = lane&15, row = (lane>>4)*4 + reg  [m89-verified].
  const int b   = bm >> 3;                               // batch
  const int tb  = (bm & 7) * 256 + wm * 128 + (l >> 4) * 4; // t of reg r=0,i=0
  const int h   = bn * 4 + wn;                           // wave-uniform head
  f16* kb = KB + ((size_t)(b * NH + h) * T_SEQ + tb) * HS + (l & 15);
#pragma unroll
  for (int i = 0; i < 8; ++i)
#pragma unroll
    for (int j = 0; j < 4; ++j)
#pragma unroll
      for (int r = 0; r < 4; ++r)
        kb[(size_t)(i * 16 + r) * HS + j * 16] = (f16)acc[i][j][r];
}

// -------------------------------------------- fused leaky-scan + L2-norm + scale
// y[t] = e^{-beta_h}*y[t-1] + k[t]; out = y/(||y||+1e-10)*scale_h.
// R12 design + R13 FIX: __syncthreads() between the LDS-transpose write and the
// cross-lane read.  (R12 NaN root-cause: phase-2 reads sq[l][d!=l] touch
// addresses this thread never wrote -> compiler may hoist them above phase-1
// writes; cross-lane LDS data needs a fence even within one wave.)
// One wave per (b,h,64-chunk); lane = dim d.
// Phase 1: recurrence in regs (64 y-regs, full unroll), y^2 -> LDS [t][d] (+1
//   pad: bank (t+d)%32, conflict-free both directions).
// Phase 2: lane = t sums its row (64 scalar ds_reads, 4-way ILP) - NO shuffles.
// Phase 3: one __shfl broadcast per t (64 total vs 320 in scan_norm2),
//   coalesced 256B/t stores.
// 64-step lookback: trunc <= exp(-0.5*64) ~ 1.3e-14  (beta_min = 0.5).
__global__ __launch_bounds__(64)
void scan_norm3(const f16* __restrict__ kb,        // (B,NH,T,HS) f16
                const float* __restrict__ beta_p,  // 16
                const float* __restrict__ ks_p,    // 16
                const int* __restrict__ sp_p,      // 1
                float* __restrict__ out) {         // (B,NH,T,HS) f32
  __shared__ float sq[64][65];                     // 16.64 KB, wave-private
  const int l = threadIdx.x;                       // lane = dim d
  const int sid = blockIdx.x;                      // 0..4095 streams
  const int c = sid & 31;          // T/64 = 32 chunks
  const int h = (sid >> 5) & 15;
  const int b = sid >> 9;

  const float beta = fabsf(beta_p[h]) * EXP_SC;
  const float a = expf(-beta);
  const float a2 = a * a, a4 = a2 * a2, a8 = a4 * a4, a16 = a8 * a8;
  const float a32 = a16 * a16;
  const float sp = (float)sp_p[0];
  const float scale = expf(fminf(sp * EXP_SC * ks_p[h], KS_MAX));

  const f16* kp = kb + (size_t)(b * NH + h) * T_SEQ * HS + l;
  float* op = out + (size_t)(b * NH + h) * T_SEQ * HS + l;

  const int t0 = c * 64;
  float y = 0.f;
  if (t0) {
    // lookback: two independent 32-chains (ILP), combined via a^32
    float p = 0.f, qq = 0.f;
#pragma unroll
    for (int s = 0; s < 32; ++s)
      p = fmaf(a, p, (float)kp[(size_t)(t0 - 64 + s) * HS]);
#pragma unroll
    for (int s = 0; s < 32; ++s)
      qq = fmaf(a, qq, (float)kp[(size_t)(t0 - 32 + s) * HS]);
    y = fmaf(p, a32, qq);
  }

  // phase 1: recurrence, y in regs (static indices - rule #20), y^2 -> LDS
  float yr[64];
#pragma unroll
  for (int t = 0; t < 64; ++t) {
    y = fmaf(a, y, (float)kp[(size_t)(t0 + t) * HS]);
    yr[t] = y;
    sq[t][l] = y * y;
  }

  __syncthreads();   // R13 FIX: fence before cross-lane LDS reads (R12 NaN)

  // phase 2: lane = t sums its row; 4 partial accumulators for ILP
  float s0 = 0.f, s1 = 0.f, s2 = 0.f, s3 = 0.f;
#pragma unroll
  for (int d = 0; d < 64; d += 4) {
    s0 += sq[l][d];     s1 += sq[l][d + 1];
    s2 += sq[l][d + 2]; s3 += sq[l][d + 3];
  }
  const float inv = scale / (sqrtf((s0 + s1) + (s2 + s3)) + 1e-10f);

  // phase 3: broadcast inv[t] (1 shfl per t), coalesced stores
#pragma unroll
  for (int t = 0; t < 64; ++t) {
    float it = __shfl(inv, t, 64);
    op[(size_t)(t0 + t) * HS] = yr[t] * it;
  }
}

// --------------------------------------------------------------- launcher
extern "C" void kernel_launch(void* const* d_in, const int* in_sizes, int n_in,
                              void* d_out, int out_size, void* d_ws, size_t ws_size,
                              hipStream_t stream) {
  const float* x      = (const float*)d_in[0];   // (8,2048,1024) f32
  const float* Wk     = (const float*)d_in[1];   // (1024,1024) f32
  const float* beta   = (const float*)d_in[2];   // (16) f32
  const float* kscale = (const float*)d_in[3];   // (16) f32
  const int*   spow   = (const int*)d_in[4];     // (1) int
  float* out = (float*)d_out;

  // workspace layout: x_f16 (32MB) | W_f16 (2MB) | kb f16 (32MB)  ~= 66MB
  f16* x_h = (f16*)d_ws;
  f16* W_h = x_h + (size_t)M_DIM * C_DIM;
  f16* kb  = W_h + (size_t)C_DIM * C_DIM;

  cast_two<<<2048, 256, 0, stream>>>(x, x_h, (M_DIM * C_DIM) / 8,
                                     Wk, W_h, (C_DIM * C_DIM) / 8);
  gemm_bt_f16_8p<<<dim3((M_DIM / 256) * (C_DIM / 256)), 512, 0, stream>>>(x_h, W_h, kb);
  scan_norm3<<<4096, 64, 0, stream>>>(kb, beta, kscale, spow, out);
}